// Round 1
// baseline (512.021 us; speedup 1.0000x reference)
//
#include <hip/hip_runtime.h>

#define NB 32
#define HW 1024
#define TSTEPS 256
#define NTHREADS 256
#define CPT 4   // cells per thread (NTHREADS*CPT == HW)
#define NWAVES (NTHREADS / 64)

__launch_bounds__(NTHREADS)
__global__ void astar_kernel(const float* __restrict__ cost,
                             const float* __restrict__ start,
                             const float* __restrict__ goal,
                             const float* __restrict__ obst,
                             float* __restrict__ out) {
    __shared__ float ls_h[HW];      // heuristic + cost (static per step)
    __shared__ float ls_g[HW];
    __shared__ float ls_cost[HW];
    __shared__ int   ls_par[HW];
    __shared__ unsigned char ls_open[HW];
    __shared__ unsigned char ls_hist[HW];
    __shared__ unsigned char ls_obst[HW];
    __shared__ unsigned char ls_path[HW];
    __shared__ float red_v[NWAVES];
    __shared__ int   red_i[NWAVES];
    __shared__ int   ls_goal;

    const int b = blockIdx.x;
    const int t = threadIdx.x;
    const float* costb  = cost  + b * HW;
    const float* startb = start + b * HW;
    const float* goalb  = goal  + b * HW;
    const float* obstb  = obst  + b * HW;

    // ---- init: load maps, find goal ----
    for (int k = 0; k < CPT; ++k) {
        int c = t + k * NTHREADS;
        float cv = costb[c];
        ls_cost[c] = cv;
        ls_g[c]    = 0.0f;
        ls_open[c] = (startb[c] > 0.5f) ? 1 : 0;
        ls_hist[c] = 0;
        ls_obst[c] = (obstb[c] > 0.5f) ? 1 : 0;
        if (goalb[c] > 0.5f) ls_goal = c;   // exactly one writer
    }
    __syncthreads();

    const int gidx = ls_goal;
    const float gi = (float)(gidx >> 5);
    const float gj = (float)(gidx & 31);

    // heuristic: max(dx,dy) + 0.001*euclid, then + cost  (match JAX op order,
    // forbid fma contraction on the one rounding-sensitive mul+add)
    for (int k = 0; k < CPT; ++k) {
        int c = t + k * NTHREADS;
        float ci = (float)(c >> 5), cj = (float)(c & 31);
        float dx = fabsf(ci - gi), dy = fabsf(cj - gj);
        float h0 = (dx + dy) - fminf(dx, dy);          // exact small ints
        float euc = sqrtf(dx * dx + dy * dy);          // exact int input
        float heur = __fadd_rn(h0, __fmul_rn(0.001f, euc));
        ls_h[c] = __fadd_rn(heur, ls_cost[c]);
        ls_par[c] = gidx;                              // parents init = goal idx
    }
    const float size_norm = 5.65685424949238019521f;   // sqrt(32), f32
    __syncthreads();

    // ---- main sequential A* scan: T = 256 steps ----
    for (int step = 0; step < TSTEPS; ++step) {
        // per-thread local argmax of val = open ? exp(-f/c) : 0
        float bv = -1.0f; int bi = 0;
        for (int k = 0; k < CPT; ++k) {
            int c = t + k * NTHREADS;
            float f = 0.5f * ls_g[c] + 0.5f * ls_h[c];   // 0.5* is exact -> fma-safe
            float e = ls_open[c] ? expf(-f / size_norm) : 0.0f;
            if (e > bv) { bv = e; bi = c; }              // ascending c => first-index tie
        }
        // wave butterfly reduce: max value, min index on ties (assoc+comm)
        #pragma unroll
        for (int off = 1; off < 64; off <<= 1) {
            float ov = __shfl_xor(bv, off);
            int   oi = __shfl_xor(bi, off);
            if (ov > bv || (ov == bv && oi < bi)) { bv = ov; bi = oi; }
        }
        if ((t & 63) == 0) { red_v[t >> 6] = bv; red_i[t >> 6] = bi; }
        __syncthreads();
        // every thread folds the wave partials (no broadcast barrier needed)
        float fv = red_v[0]; int fi = red_i[0];
        #pragma unroll
        for (int w = 1; w < NWAVES; ++w) {
            float ov = red_v[w]; int oi = red_i[w];
            if (ov > fv || (ov == fv && oi < fi)) { fv = ov; fi = oi; }
        }
        const int s = fi;
        const int unsolved = (s != gidx);
        const float gval = ls_g[s] + ls_cost[s];   // g[s] never written this step
        const int si = s >> 5, sj = s & 31;

        for (int k = 0; k < CPT; ++k) {
            int c = t + k * NTHREADS;
            if (c == s) {
                ls_hist[c] = 1;                     // hist |= sel
                if (unsolved) ls_open[c] = 0;       // open -= is_unsolved*sel
            }
            int di = (c >> 5) - si, dj = (c & 31) - sj;
            bool nb = (di >= -1) && (di <= 1) && (dj >= -1) && (dj <= 1) &&
                      !((di == 0) && (dj == 0)) && ls_obst[c];
            if (nb) {
                // idx = (1-open)(1-hist)*nb  OR  open*nb*(g2<g)
                bool i1 = (!ls_open[c]) && (!ls_hist[c]);
                bool i2 = ls_open[c] && (gval < ls_g[c]);
                if (i1 || i2) {
                    ls_g[c]    = gval;
                    ls_open[c] = 1;
                    ls_par[c]  = s;
                }
            }
        }
        __syncthreads();
    }

    // ---- backtrack: path = {goal}; loc = par[goal]; 256 pointer-chase steps ----
    for (int k = 0; k < CPT; ++k) {
        int c = t + k * NTHREADS;
        ls_path[c] = (c == gidx) ? 1 : 0;
    }
    __syncthreads();
    if (t == 0) {
        int loc = ls_par[gidx];
        for (int it = 0; it < TSTEPS; ++it) {
            ls_path[loc] = 1;
            loc = ls_par[loc];
        }
    }
    __syncthreads();

    // ---- write outputs: [histories (B*HW) | path (B*HW)], all f32 0/1 ----
    float* hout = out + b * HW;
    float* pout = out + NB * HW + b * HW;
    for (int k = 0; k < CPT; ++k) {
        int c = t + k * NTHREADS;
        hout[c] = (float)ls_hist[c];
        pout[c] = (float)ls_path[c];
    }
}

extern "C" void kernel_launch(void* const* d_in, const int* in_sizes, int n_in,
                              void* d_out, int out_size, void* d_ws, size_t ws_size,
                              hipStream_t stream) {
    (void)in_sizes; (void)n_in; (void)d_ws; (void)ws_size; (void)out_size;
    const float* cost  = (const float*)d_in[0];
    const float* start = (const float*)d_in[1];
    const float* goal  = (const float*)d_in[2];
    const float* obst  = (const float*)d_in[3];
    float* out = (float*)d_out;
    astar_kernel<<<dim3(NB), dim3(NTHREADS), 0, stream>>>(cost, start, goal, obst, out);
}

// Round 2
// 344.484 us; speedup vs baseline: 1.4863x; 1.4863x over previous
//
#include <hip/hip_runtime.h>

#define HW 1024
#define TSTEPS 256
#define NS 16            // slots per lane (64 lanes * 16 = 1024 cells)
#define SIZE_NORM 5.65685424949238019521f

// u32 max (positive-float bit order == u32 order)
__device__ __forceinline__ unsigned umax2(unsigned a, unsigned b) { return a > b ? a : b; }
__device__ __forceinline__ unsigned umax3(unsigned a, unsigned b, unsigned c) {
    return umax2(umax2(a, b), c);   // compiler fuses to v_max3_u32
}

__device__ __forceinline__ float e_of(float g, float h) {
    float f = 0.5f * g + 0.5f * h;          // identical to passing round-1 formula
    return expf(-f / SIZE_NORM);
}

// butterfly-equivalent max across one 16-lane row via DPP (VALU speed, no LDS)
#define DPP_MAX(v, ctrl)                                                          \
    do {                                                                          \
        unsigned _o = (unsigned)__builtin_amdgcn_mov_dpp((int)(v), (ctrl), 0xF, 0xF, false); \
        (v) = umax2((v), _o);                                                     \
    } while (0)

__launch_bounds__(64)
__global__ void astar_kernel(const float* __restrict__ cost,
                             const float* __restrict__ start,
                             const float* __restrict__ goal,
                             const float* __restrict__ obst,
                             float* __restrict__ out) {
    __shared__ int   ls_par[HW];
    __shared__ float ls_gc[HW];              // g[c] + cost[c] mirror for gval broadcast
    __shared__ unsigned char ls_m[HW];       // backtrack marks

    const int b    = blockIdx.x;
    const int lane = threadIdx.x;            // 0..63
    const float* costb  = cost  + b * HW;
    const float* startb = start + b * HW;
    const float* goalb  = goal  + b * HW;
    const float* obstb  = obst  + b * HW;

    float    cst[NS], h[NS], g[NS];
    unsigned ebits[NS];
    unsigned openm = 0, histm = 0, obstm = 0, goalm = 0;

    // ---- init: coalesced loads, build bit-masks ----
    #pragma unroll
    for (int k = 0; k < NS; ++k) {
        int c = k * 64 + lane;
        cst[k] = costb[c];
        g[k]   = 0.0f;
        openm |= (startb[c] > 0.5f ? 1u : 0u) << k;
        obstm |= (obstb[c]  > 0.5f ? 1u : 0u) << k;
        goalm |= (goalb[c]  > 0.5f ? 1u : 0u) << k;
    }
    // goal index: descending k so the smallest matching k wins (exactly one set anyway)
    int gidx = 0;
    #pragma unroll
    for (int k = NS - 1; k >= 0; --k) {
        unsigned long long m = __ballot((goalm >> k) & 1u);
        if (m) gidx = k * 64 + (int)(__ffsll((unsigned long long)m) - 1);
    }

    const float gi = (float)(gidx >> 5), gj = (float)(gidx & 31);
    #pragma unroll
    for (int k = 0; k < NS; ++k) {
        int c = k * 64 + lane;
        float ci = (float)(c >> 5), cj = (float)(c & 31);
        float dx = fabsf(ci - gi), dy = fabsf(cj - gj);
        float h0 = (dx + dy) - fminf(dx, dy);
        float euc = sqrtf(dx * dx + dy * dy);
        float heur = __fadd_rn(h0, __fmul_rn(0.001f, euc));
        h[k] = __fadd_rn(heur, cst[k]);                       // h = heuristic + cost
        ebits[k] = ((openm >> k) & 1u) ? __float_as_uint(e_of(0.0f, h[k])) : 0u;
        ls_par[c] = gidx;
        ls_gc[c]  = cst[k];                                   // g=0 + cost
    }
    __syncthreads();

    // ---- main sequential scan: 256 steps ----
    for (int step = 0; step < TSTEPS; ++step) {
        // local max over 16 register slots (v_max3_u32 tree)
        unsigned m0 = umax3(ebits[0],  ebits[1],  ebits[2]);
        unsigned m1 = umax3(ebits[3],  ebits[4],  ebits[5]);
        unsigned m2 = umax3(ebits[6],  ebits[7],  ebits[8]);
        unsigned m3 = umax3(ebits[9],  ebits[10], ebits[11]);
        unsigned m4 = umax3(ebits[12], ebits[13], ebits[14]);
        unsigned lm = umax2(umax3(m0, m1, m2), umax3(m3, m4, ebits[15]));

        // cross-lane max: xor1, xor2 (quad_perm), xor7 (row_half_mirror), xor8 (row_ror:8)
        DPP_MAX(lm, 0xB1);    // quad_perm [1,0,3,2]
        DPP_MAX(lm, 0x4E);    // quad_perm [2,3,0,1]
        DPP_MAX(lm, 0x141);   // row_half_mirror (xor 7)
        DPP_MAX(lm, 0x128);   // row_ror:8 (xor 8 within 16)
        unsigned r0 = (unsigned)__builtin_amdgcn_readlane((int)lm, 0);
        unsigned r1 = (unsigned)__builtin_amdgcn_readlane((int)lm, 16);
        unsigned r2 = (unsigned)__builtin_amdgcn_readlane((int)lm, 32);
        unsigned r3 = (unsigned)__builtin_amdgcn_readlane((int)lm, 48);
        unsigned gmax = umax2(umax2(r0, r1), umax2(r2, r3));

        // first (min-index) cell with ebits == gmax: ascending slot, ctz over lanes
        int s_sel = 0;
        #pragma unroll
        for (int k = 0; k < NS; ++k) {
            unsigned long long mm = __ballot(ebits[k] == gmax);
            if (mm) { s_sel = k * 64 + (int)(__ffsll(mm) - 1); break; }
        }

        const int  si = s_sel >> 5, sj = s_sel & 31;
        const int  k_s = s_sel >> 6, lane_s = s_sel & 63;
        const bool unsolved = (s_sel != gidx);
        const float gval = ls_gc[s_sel];                 // broadcast ds_read
        const int k0 = (si > 0  ? si - 1 : 0)  >> 1;
        const int k1 = (si < 31 ? si + 1 : 31) >> 1;

        #pragma unroll
        for (int k = 0; k < NS; ++k) {
            if (k < k0 || k > k1) continue;              // wave-uniform skip (<=2 slots run)
            const int c   = k * 64 + lane;
            const int row = (k << 1) + (lane >> 5);
            const int col = lane & 31;
            const int di = row - si, dj = col - sj;
            bool nb = ((unsigned)(di + 1) <= 2u) && ((unsigned)(dj + 1) <= 2u) &&
                      ((di | dj) != 0) && ((obstm >> k) & 1u);
            bool op = (openm >> k) & 1u;
            bool hs = (histm >> k) & 1u;
            bool sel = nb && ((!op && !hs) || (op && (gval < g[k])));
            float enew = e_of(gval, h[k]);
            if (sel) {
                g[k] = gval;
                openm |= 1u << k;
                ebits[k] = __float_as_uint(enew);
                ls_par[c] = s_sel;
                ls_gc[c]  = gval + cst[k];
            }
            if (k == k_s) {                              // uniform; k_s in [k0,k1] always
                if (lane == lane_s) {
                    histm |= 1u << k;
                    if (unsolved) { openm &= ~(1u << k); ebits[k] = 0u; }
                }
            }
        }
        __syncthreads();   // single wave: degenerates to waitcnt fence, orders LDS
    }

    // ---- backtrack via pointer doubling: marks {par^i(A0) : 0<=i<256} + goal ----
    #pragma unroll
    for (int k = 0; k < NS; ++k) { int c = k * 64 + lane; ls_m[c] = (c == gidx) ? 1 : 0; }
    __syncthreads();
    int A0 = ls_par[gidx];
    if (lane == 0) ls_m[A0] = 1;
    __syncthreads();

    for (int j = 0; j < 8; ++j) {                        // 2^8 = 256 = TSTEPS
        int pk[NS], pp[NS]; unsigned mk = 0;
        #pragma unroll
        for (int k = 0; k < NS; ++k) { int c = k * 64 + lane; pk[k] = ls_par[c]; }
        #pragma unroll
        for (int k = 0; k < NS; ++k) { pp[k] = ls_par[pk[k]]; }
        #pragma unroll
        for (int k = 0; k < NS; ++k) { int c = k * 64 + lane; mk |= (unsigned)ls_m[c] << k; }
        __syncthreads();
        #pragma unroll
        for (int k = 0; k < NS; ++k) { if ((mk >> k) & 1u) ls_m[pk[k]] = 1; }
        #pragma unroll
        for (int k = 0; k < NS; ++k) { int c = k * 64 + lane; ls_par[c] = pp[k]; }
        __syncthreads();
    }

    // ---- outputs: [histories | path], f32 0/1 ----
    float* hout = out + (size_t)b * HW;
    float* pout = out + (size_t)gridDim.x * HW + (size_t)b * HW;
    #pragma unroll
    for (int k = 0; k < NS; ++k) {
        int c = k * 64 + lane;
        hout[c] = (float)((histm >> k) & 1u);
        pout[c] = (float)ls_m[c];
    }
}

extern "C" void kernel_launch(void* const* d_in, const int* in_sizes, int n_in,
                              void* d_out, int out_size, void* d_ws, size_t ws_size,
                              hipStream_t stream) {
    (void)n_in; (void)d_ws; (void)ws_size; (void)out_size;
    const float* cost  = (const float*)d_in[0];
    const float* start = (const float*)d_in[1];
    const float* goal  = (const float*)d_in[2];
    const float* obst  = (const float*)d_in[3];
    float* out = (float*)d_out;
    const int nb = in_sizes[0] / HW;
    astar_kernel<<<dim3(nb), dim3(64), 0, stream>>>(cost, start, goal, obst, out);
}

// Round 3
// 270.958 us; speedup vs baseline: 1.8897x; 1.2714x over previous
//
#include <hip/hip_runtime.h>

#define HW 1024
#define TSTEPS 256
#define NS 16            // slots per lane (64 lanes * 16 = 1024 cells)
#define SIZE_NORM 5.65685424949238019521f

__device__ __forceinline__ unsigned umax2(unsigned a, unsigned b) { return a > b ? a : b; }
__device__ __forceinline__ unsigned umax3(unsigned a, unsigned b, unsigned c) {
    return umax2(umax2(a, b), c);   // v_max3_u32
}

// bit-identical to the passing rounds
__device__ __forceinline__ float e_of(float g, float h) {
    float f = 0.5f * g + 0.5f * h;
    return expf(-f / SIZE_NORM);
}

#define DPP_MAX(v, ctrl)                                                                     \
    do {                                                                                     \
        unsigned _o = (unsigned)__builtin_amdgcn_mov_dpp((int)(v), (ctrl), 0xF, 0xF, false); \
        (v) = umax2((v), _o);                                                                \
    } while (0)

__launch_bounds__(64)
__global__ void astar_kernel(const float* __restrict__ cost,
                             const float* __restrict__ start,
                             const float* __restrict__ goal,
                             const float* __restrict__ obst,
                             float* __restrict__ out) {
    __shared__ int   ls_par[HW];
    __shared__ unsigned char ls_m[HW];

    const int b    = blockIdx.x;
    const int lane = threadIdx.x;            // 0..63
    const float* costb  = cost  + b * HW;
    const float* startb = start + b * HW;
    const float* goalb  = goal  + b * HW;
    const float* obstb  = obst  + b * HW;

    float    cst[NS], h[NS], g[NS], gc[NS];
    unsigned ebits[NS];
    int      par[NS];
    unsigned openm = 0, histm = 0, obstm = 0, goalm = 0;

    // ---- init: coalesced loads, bit-masks ----
    #pragma unroll
    for (int k = 0; k < NS; ++k) {
        int c = k * 64 + lane;
        cst[k] = costb[c];
        g[k]   = 0.0f;
        openm |= (startb[c] > 0.5f ? 1u : 0u) << k;
        obstm |= (obstb[c]  > 0.5f ? 1u : 0u) << k;
        goalm |= (goalb[c]  > 0.5f ? 1u : 0u) << k;
    }
    int gidx = 0;
    #pragma unroll
    for (int k = NS - 1; k >= 0; --k) {
        unsigned long long m = __ballot((goalm >> k) & 1u);
        if (m) gidx = k * 64 + (int)(__ffsll(m) - 1);
    }

    const float gi = (float)(gidx >> 5), gj = (float)(gidx & 31);
    #pragma unroll
    for (int k = 0; k < NS; ++k) {
        int c = k * 64 + lane;
        float ci = (float)(c >> 5), cj = (float)(c & 31);
        float dx = fabsf(ci - gi), dy = fabsf(cj - gj);
        float h0 = (dx + dy) - fminf(dx, dy);
        float euc = sqrtf(dx * dx + dy * dy);
        float heur = __fadd_rn(h0, __fmul_rn(0.001f, euc));
        h[k]  = __fadd_rn(heur, cst[k]);
        ebits[k] = ((openm >> k) & 1u) ? __float_as_uint(e_of(0.0f, h[k])) : 0u;
        gc[k] = cst[k];                       // g=0 + cost
        par[k] = gidx;
    }

    // ---- main scan: 256 steps, zero LDS, zero barriers ----
    for (int step = 0; step < TSTEPS; ++step) {
        // local max over 16 slots (static indices only)
        unsigned m0 = umax3(ebits[0],  ebits[1],  ebits[2]);
        unsigned m1 = umax3(ebits[3],  ebits[4],  ebits[5]);
        unsigned m2 = umax3(ebits[6],  ebits[7],  ebits[8]);
        unsigned m3 = umax3(ebits[9],  ebits[10], ebits[11]);
        unsigned m4 = umax3(ebits[12], ebits[13], ebits[14]);
        unsigned lm = umax2(umax3(m0, m1, m2), umax3(m3, m4, ebits[15]));

        // cross-lane max via DPP butterfly within 16-lane rows, then scalar combine
        DPP_MAX(lm, 0xB1);    // quad_perm xor1
        DPP_MAX(lm, 0x4E);    // quad_perm xor2
        DPP_MAX(lm, 0x141);   // row_half_mirror
        DPP_MAX(lm, 0x128);   // row_ror:8
        unsigned r0 = (unsigned)__builtin_amdgcn_readlane((int)lm, 0);
        unsigned r1 = (unsigned)__builtin_amdgcn_readlane((int)lm, 16);
        unsigned r2 = (unsigned)__builtin_amdgcn_readlane((int)lm, 32);
        unsigned r3 = (unsigned)__builtin_amdgcn_readlane((int)lm, 48);
        unsigned gmax = umax2(umax2(r0, r1), umax2(r2, r3));

        // first (min-index) matching cell: unrolled ballots, descending scalar select
        int s_sel = 0;
        #pragma unroll
        for (int k = NS - 1; k >= 0; --k) {
            unsigned long long mm = __ballot(ebits[k] == gmax);
            if (mm) s_sel = k * 64 + (int)(__ffsll(mm) - 1);
        }

        const int  k_s = s_sel >> 6, lane_s = s_sel & 63;
        const int  si  = s_sel >> 5, sj = s_sel & 31;
        const bool unsolved = (s_sel != gidx);

        // gval = g[s]+cost[s]: uniform switch + readlane (no LDS, no dynamic reg index)
        int gvb;
        switch (k_s) {
            case 0:  gvb = __builtin_amdgcn_readlane(__float_as_int(gc[0]),  lane_s); break;
            case 1:  gvb = __builtin_amdgcn_readlane(__float_as_int(gc[1]),  lane_s); break;
            case 2:  gvb = __builtin_amdgcn_readlane(__float_as_int(gc[2]),  lane_s); break;
            case 3:  gvb = __builtin_amdgcn_readlane(__float_as_int(gc[3]),  lane_s); break;
            case 4:  gvb = __builtin_amdgcn_readlane(__float_as_int(gc[4]),  lane_s); break;
            case 5:  gvb = __builtin_amdgcn_readlane(__float_as_int(gc[5]),  lane_s); break;
            case 6:  gvb = __builtin_amdgcn_readlane(__float_as_int(gc[6]),  lane_s); break;
            case 7:  gvb = __builtin_amdgcn_readlane(__float_as_int(gc[7]),  lane_s); break;
            case 8:  gvb = __builtin_amdgcn_readlane(__float_as_int(gc[8]),  lane_s); break;
            case 9:  gvb = __builtin_amdgcn_readlane(__float_as_int(gc[9]),  lane_s); break;
            case 10: gvb = __builtin_amdgcn_readlane(__float_as_int(gc[10]), lane_s); break;
            case 11: gvb = __builtin_amdgcn_readlane(__float_as_int(gc[11]), lane_s); break;
            case 12: gvb = __builtin_amdgcn_readlane(__float_as_int(gc[12]), lane_s); break;
            case 13: gvb = __builtin_amdgcn_readlane(__float_as_int(gc[13]), lane_s); break;
            case 14: gvb = __builtin_amdgcn_readlane(__float_as_int(gc[14]), lane_s); break;
            default: gvb = __builtin_amdgcn_readlane(__float_as_int(gc[15]), lane_s); break;
        }
        const float gval = __int_as_float(gvb);

        const int k0 = (si > 0  ? si - 1 : 0)  >> 1;
        const int k1 = (si < 31 ? si + 1 : 31) >> 1;

        #pragma unroll
        for (int k = 0; k < NS; ++k) {
            if (k >= k0 && k <= k1) {          // wave-uniform skip; <=2 bodies execute
                const int row = (k << 1) + (lane >> 5);
                const int col = lane & 31;
                const int di = row - si, dj = col - sj;
                bool nb = ((unsigned)(di + 1) <= 2u) && ((unsigned)(dj + 1) <= 2u) &&
                          ((di | dj) != 0) && ((obstm >> k) & 1u);
                bool op = (openm >> k) & 1u;
                bool hs = (histm >> k) & 1u;
                bool sel = nb && ((!op && !hs) || (op && (gval < g[k])));
                if (sel) {
                    g[k]  = gval;
                    gc[k] = gval + cst[k];
                    openm |= 1u << k;
                    ebits[k] = __float_as_uint(e_of(gval, h[k]));
                    par[k] = s_sel;
                }
                if (k == k_s && lane == lane_s) {
                    histm |= 1u << k;
                    if (unsolved) { openm &= ~(1u << k); ebits[k] = 0u; }
                }
            }
        }
    }

    // ---- dump parents, backtrack via pointer doubling ----
    #pragma unroll
    for (int k = 0; k < NS; ++k) {
        int c = k * 64 + lane;
        ls_par[c] = par[k];
        ls_m[c]   = (c == gidx) ? 1 : 0;
    }
    __syncthreads();
    int A0 = ls_par[gidx];
    if (lane == 0) ls_m[A0] = 1;
    __syncthreads();

    for (int j = 0; j < 8; ++j) {            // 2^8 = 256 = TSTEPS
        int pk[NS], pp[NS]; unsigned mk = 0;
        #pragma unroll
        for (int k = 0; k < NS; ++k) { int c = k * 64 + lane; pk[k] = ls_par[c]; }
        #pragma unroll
        for (int k = 0; k < NS; ++k) { pp[k] = ls_par[pk[k]]; }
        #pragma unroll
        for (int k = 0; k < NS; ++k) { int c = k * 64 + lane; mk |= (unsigned)ls_m[c] << k; }
        __syncthreads();
        #pragma unroll
        for (int k = 0; k < NS; ++k) { if ((mk >> k) & 1u) ls_m[pk[k]] = 1; }
        #pragma unroll
        for (int k = 0; k < NS; ++k) { int c = k * 64 + lane; ls_par[c] = pp[k]; }
        __syncthreads();
    }

    // ---- outputs: [histories | path], f32 0/1 ----
    float* hout = out + (size_t)b * HW;
    float* pout = out + (size_t)gridDim.x * HW + (size_t)b * HW;
    #pragma unroll
    for (int k = 0; k < NS; ++k) {
        int c = k * 64 + lane;
        hout[c] = (float)((histm >> k) & 1u);
        pout[c] = (float)ls_m[c];
    }
}

extern "C" void kernel_launch(void* const* d_in, const int* in_sizes, int n_in,
                              void* d_out, int out_size, void* d_ws, size_t ws_size,
                              hipStream_t stream) {
    (void)n_in; (void)d_ws; (void)ws_size; (void)out_size;
    const float* cost  = (const float*)d_in[0];
    const float* start = (const float*)d_in[1];
    const float* goal  = (const float*)d_in[2];
    const float* obst  = (const float*)d_in[3];
    float* out = (float*)d_out;
    const int nb = in_sizes[0] / HW;
    astar_kernel<<<dim3(nb), dim3(64), 0, stream>>>(cost, start, goal, obst, out);
}

// Round 4
// 268.398 us; speedup vs baseline: 1.9077x; 1.0095x over previous
//
#include <hip/hip_runtime.h>

#define HW 1024
#define TSTEPS 256
#define NS 16            // slots per lane (64 lanes * 16 = 1024 cells)
#define SIZE_NORM 5.65685424949238019521f

__device__ __forceinline__ unsigned umax2(unsigned a, unsigned b) { return a > b ? a : b; }
__device__ __forceinline__ unsigned umax3(unsigned a, unsigned b, unsigned c) {
    return umax2(umax2(a, b), c);   // v_max3_u32
}

// bit-identical to the passing rounds
__device__ __forceinline__ float e_of(float g, float h) {
    float f = 0.5f * g + 0.5f * h;
    return expf(-f / SIZE_NORM);
}

#define DPP_MAX(v, ctrl)                                                                     \
    do {                                                                                     \
        unsigned _o = (unsigned)__builtin_amdgcn_mov_dpp((int)(v), (ctrl), 0xF, 0xF, false); \
        (v) = umax2((v), _o);                                                                \
    } while (0)

__launch_bounds__(64, 1)   // 1 wave/EU min -> allocator may use full VGPR budget (no spill)
__global__ void astar_kernel(const float* __restrict__ cost,
                             const float* __restrict__ start,
                             const float* __restrict__ goal,
                             const float* __restrict__ obst,
                             float* __restrict__ out) {
    __shared__ int   ls_par[HW];
    __shared__ unsigned char ls_m[HW];

    const int b    = blockIdx.x;
    const int lane = threadIdx.x;            // 0..63
    const float* costb  = cost  + b * HW;
    const float* startb = start + b * HW;
    const float* goalb  = goal  + b * HW;
    const float* obstb  = obst  + b * HW;

    float    cst[NS], h[NS], g[NS];
    unsigned ebits[NS];
    unsigned openm = 0, histm = 0, obstm = 0, goalm = 0;

    // ---- init: coalesced loads, bit-masks ----
    #pragma unroll
    for (int k = 0; k < NS; ++k) {
        int c = k * 64 + lane;
        cst[k] = costb[c];
        g[k]   = 0.0f;
        openm |= (startb[c] > 0.5f ? 1u : 0u) << k;
        obstm |= (obstb[c]  > 0.5f ? 1u : 0u) << k;
        goalm |= (goalb[c]  > 0.5f ? 1u : 0u) << k;
    }
    int gidx = 0;
    #pragma unroll
    for (int k = NS - 1; k >= 0; --k) {
        unsigned long long m = __ballot((goalm >> k) & 1u);
        if (m) gidx = k * 64 + (int)(__ffsll(m) - 1);
    }

    const float gi = (float)(gidx >> 5), gj = (float)(gidx & 31);
    #pragma unroll
    for (int k = 0; k < NS; ++k) {
        int c = k * 64 + lane;
        float ci = (float)(c >> 5), cj = (float)(c & 31);
        float dx = fabsf(ci - gi), dy = fabsf(cj - gj);
        float h0 = (dx + dy) - fminf(dx, dy);
        float euc = sqrtf(dx * dx + dy * dy);
        float heur = __fadd_rn(h0, __fmul_rn(0.001f, euc));
        h[k]  = __fadd_rn(heur, cst[k]);
        ebits[k] = ((openm >> k) & 1u) ? __float_as_uint(e_of(0.0f, h[k])) : 0u;
        ls_par[c] = gidx;                    // parents live in LDS (write-only in loop)
    }

    // ---- main scan: 256 steps; state in VGPRs, parents via ds_write only ----
    for (int step = 0; step < TSTEPS; ++step) {
        // local max over 16 slots (static indices only)
        unsigned m0 = umax3(ebits[0],  ebits[1],  ebits[2]);
        unsigned m1 = umax3(ebits[3],  ebits[4],  ebits[5]);
        unsigned m2 = umax3(ebits[6],  ebits[7],  ebits[8]);
        unsigned m3 = umax3(ebits[9],  ebits[10], ebits[11]);
        unsigned m4 = umax3(ebits[12], ebits[13], ebits[14]);
        unsigned lm = umax2(umax3(m0, m1, m2), umax3(m3, m4, ebits[15]));

        // cross-lane max via DPP butterfly within 16-lane rows, then scalar combine
        DPP_MAX(lm, 0xB1);    // quad_perm xor1
        DPP_MAX(lm, 0x4E);    // quad_perm xor2
        DPP_MAX(lm, 0x141);   // row_half_mirror
        DPP_MAX(lm, 0x128);   // row_ror:8
        unsigned r0 = (unsigned)__builtin_amdgcn_readlane((int)lm, 0);
        unsigned r1 = (unsigned)__builtin_amdgcn_readlane((int)lm, 16);
        unsigned r2 = (unsigned)__builtin_amdgcn_readlane((int)lm, 32);
        unsigned r3 = (unsigned)__builtin_amdgcn_readlane((int)lm, 48);
        unsigned gmax = umax2(umax2(r0, r1), umax2(r2, r3));

        // first (min-index) matching cell: unrolled ballots, descending scalar select
        int s_sel = 0;
        #pragma unroll
        for (int k = NS - 1; k >= 0; --k) {
            unsigned long long mm = __ballot(ebits[k] == gmax);
            if (mm) s_sel = k * 64 + (int)(__ffsll(mm) - 1);
        }

        const int  k_s = s_sel >> 6, lane_s = s_sel & 63;
        const int  si  = s_sel >> 5, sj = s_sel & 31;
        const bool unsolved = (s_sel != gidx);

        // gval = g[s] + cost[s]: uniform switch + two dynamic-lane readlanes
        int g_b, c_b;
        switch (k_s) {
#define RL_CASE(K)                                                                 \
            case K:                                                                \
                g_b = __builtin_amdgcn_readlane(__float_as_int(g[K]),   lane_s);   \
                c_b = __builtin_amdgcn_readlane(__float_as_int(cst[K]), lane_s);   \
                break;
            RL_CASE(0)  RL_CASE(1)  RL_CASE(2)  RL_CASE(3)
            RL_CASE(4)  RL_CASE(5)  RL_CASE(6)  RL_CASE(7)
            RL_CASE(8)  RL_CASE(9)  RL_CASE(10) RL_CASE(11)
            RL_CASE(12) RL_CASE(13) RL_CASE(14)
            default:
                g_b = __builtin_amdgcn_readlane(__float_as_int(g[15]),   lane_s);
                c_b = __builtin_amdgcn_readlane(__float_as_int(cst[15]), lane_s);
                break;
#undef RL_CASE
        }
        const float gval = __int_as_float(g_b) + __int_as_float(c_b);

        const int k0 = (si > 0  ? si - 1 : 0)  >> 1;
        const int k1 = (si < 31 ? si + 1 : 31) >> 1;

        #pragma unroll
        for (int k = 0; k < NS; ++k) {
            if (k >= k0 && k <= k1) {          // wave-uniform skip; <=2 bodies execute
                const int row = (k << 1) + (lane >> 5);
                const int col = lane & 31;
                const int di = row - si, dj = col - sj;
                bool nb = ((unsigned)(di + 1) <= 2u) && ((unsigned)(dj + 1) <= 2u) &&
                          ((di | dj) != 0) && ((obstm >> k) & 1u);
                bool op = (openm >> k) & 1u;
                bool hs = (histm >> k) & 1u;
                bool sel = nb && ((!op && !hs) || (op && (gval < g[k])));
                if (sel) {
                    g[k]  = gval;
                    openm |= 1u << k;
                    ebits[k] = __float_as_uint(e_of(gval, h[k]));
                    ls_par[k * 64 + lane] = s_sel;     // write-only ds_write
                }
                if (k == k_s && lane == lane_s) {
                    histm |= 1u << k;
                    if (unsolved) { openm &= ~(1u << k); ebits[k] = 0u; }
                }
            }
        }
    }

    // ---- backtrack via pointer doubling ----
    #pragma unroll
    for (int k = 0; k < NS; ++k) {
        int c = k * 64 + lane;
        ls_m[c] = (c == gidx) ? 1 : 0;
    }
    __syncthreads();
    int A0 = ls_par[gidx];
    if (lane == 0) ls_m[A0] = 1;
    __syncthreads();

    for (int j = 0; j < 8; ++j) {            // 2^8 = 256 = TSTEPS
        int pk[NS], pp[NS]; unsigned mk = 0;
        #pragma unroll
        for (int k = 0; k < NS; ++k) { int c = k * 64 + lane; pk[k] = ls_par[c]; }
        #pragma unroll
        for (int k = 0; k < NS; ++k) { pp[k] = ls_par[pk[k]]; }
        #pragma unroll
        for (int k = 0; k < NS; ++k) { int c = k * 64 + lane; mk |= (unsigned)ls_m[c] << k; }
        __syncthreads();
        #pragma unroll
        for (int k = 0; k < NS; ++k) { if ((mk >> k) & 1u) ls_m[pk[k]] = 1; }
        #pragma unroll
        for (int k = 0; k < NS; ++k) { int c = k * 64 + lane; ls_par[c] = pp[k]; }
        __syncthreads();
    }

    // ---- outputs: [histories | path], f32 0/1 ----
    float* hout = out + (size_t)b * HW;
    float* pout = out + (size_t)gridDim.x * HW + (size_t)b * HW;
    #pragma unroll
    for (int k = 0; k < NS; ++k) {
        int c = k * 64 + lane;
        hout[c] = (float)((histm >> k) & 1u);
        pout[c] = (float)ls_m[c];
    }
}

extern "C" void kernel_launch(void* const* d_in, const int* in_sizes, int n_in,
                              void* d_out, int out_size, void* d_ws, size_t ws_size,
                              hipStream_t stream) {
    (void)n_in; (void)d_ws; (void)ws_size; (void)out_size;
    const float* cost  = (const float*)d_in[0];
    const float* start = (const float*)d_in[1];
    const float* goal  = (const float*)d_in[2];
    const float* obst  = (const float*)d_in[3];
    float* out = (float*)d_out;
    const int nb = in_sizes[0] / HW;
    astar_kernel<<<dim3(nb), dim3(64), 0, stream>>>(cost, start, goal, obst, out);
}